// Round 8
// baseline (196.348 us; speedup 1.0000x reference)
//
#include <hip/hip_runtime.h>
#include <hip/hip_bf16.h>

#define DD 128    // feature dim
#define HH 16     // hidden dim
#define BW 128    // bucket width (nodes per bucket) = 1<<7
#define NBMAX 1024
#define GAPB 4096      // fixed per-bucket slot capacity (avg fill 2048, max ~2300)
#define SCAP 4096      // LDS slice cap in sortagg
#define XG 1024        // xform grid

// bf16x2 pack/unpack (RNE)
__device__ __forceinline__ float lo16(unsigned u) { return __uint_as_float(u << 16); }
__device__ __forceinline__ float hi16(unsigned u) { return __uint_as_float(u & 0xffff0000u); }
__device__ __forceinline__ unsigned b16(float f) {
    unsigned u = __float_as_uint(f);
    return (u + 0x7fffu + ((u >> 16) & 1u)) >> 16;
}
__device__ __forceinline__ unsigned pack2(float a, float b) {
    return b16(a) | (b16(b) << 16);
}

typedef __attribute__((ext_vector_type(8))) short bf16x8;   // MFMA A/B frag (4 VGPRs)
typedef __attribute__((ext_vector_type(4))) float f32x4;    // MFMA C/D frag

// ---------------------------------------------------------------------------
// K1 (k_scat): gapped-bucket single-pass scatter, 2048 edges/block (783
// blocks = 3 blocks/CU — the kernel is latency-bound, so maximize block-level
// concurrency; R6's 8192-edge/98-block variant starved the machine).
// Reservation: (b<<12) + atomicAdd(&bcnt[b], localCount).
// Block cblocks does the classifier-collapse prep (wsu[0..65]).
// ---------------------------------------------------------------------------
__global__ __launch_bounds__(256) void k_scat(const int* __restrict__ src,
                                              const int* __restrict__ dst,
                                              int* __restrict__ bcnt,
                                              int* __restrict__ packed,
                                              int E4, int NB, int cblocks,
                                              const float* __restrict__ w2l,
                                              const float* __restrict__ w2r,
                                              const float* __restrict__ b2v,
                                              const float* __restrict__ wc,
                                              const float* __restrict__ bc,
                                              float* __restrict__ wsu) {
    const int tid = threadIdx.x;
    const int bid = (int)blockIdx.x;

    if (bid == cblocks) {      // ---- prep block ----
        if (tid < 64) {
            int k = tid >> 4, j = tid & 15;
            const float* W = (k < 2) ? w2l : w2r;
            int off = (k & 1) * DD;
            float s = 0.f;
            for (int d = 0; d < DD; ++d) s += W[j * DD + d] * wc[off + d];
            wsu[k * 16 + j] = s;
        } else if (tid == 64) {
            float s = bc[0];
            for (int d = 0; d < DD; ++d) s += b2v[d] * wc[d];
            wsu[64] = s;
        } else if (tid == 65) {
            float s = 0.f;
            for (int d = 0; d < DD; ++d) s += b2v[d] * wc[DD + d];
            wsu[65] = s;
        }
        return;
    }

    __shared__ int hist[NBMAX];
    __shared__ int cur[NBMAX];
    for (int i = tid; i < NB; i += 256) hist[i] = 0;
    __syncthreads();
    int base = bid * 512;                     // int4 units: 2048 edges/block
    int4 dreg[2];
#pragma unroll
    for (int k = 0; k < 2; ++k) {
        int i4 = base + k * 256 + tid;
        if (i4 < E4) {
            int4 d = ((const int4*)dst)[i4];
            dreg[k] = d;
            atomicAdd(&hist[d.x >> 7], 1);
            atomicAdd(&hist[d.y >> 7], 1);
            atomicAdd(&hist[d.z >> 7], 1);
            atomicAdd(&hist[d.w >> 7], 1);
        }
    }
    __syncthreads();
    // reserve per-bucket ranges directly in the gapped global layout
    for (int i = tid; i < NB; i += 256) {
        int hv = hist[i];
        cur[i] = hv ? (i << 12) + atomicAdd(&bcnt[i], hv) : 0;
    }
    __syncthreads();
#pragma unroll
    for (int k = 0; k < 2; ++k) {
        int i4 = base + k * 256 + tid;
        if (i4 < E4) {
            int4 sv = ((const int4*)src)[i4];
            int4 d = dreg[k];
            int p;
            p = atomicAdd(&cur[d.x >> 7], 1); packed[p] = ((d.x & 127) << 20) | sv.x;
            p = atomicAdd(&cur[d.y >> 7], 1); packed[p] = ((d.y & 127) << 20) | sv.y;
            p = atomicAdd(&cur[d.z >> 7], 1); packed[p] = ((d.z & 127) << 20) | sv.z;
            p = atomicAdd(&cur[d.w >> 7], 1); packed[p] = ((d.w & 127) << 20) | sv.w;
        }
    }
}

// ---------------------------------------------------------------------------
// K4 (k_xform): standalone (own regalloc -> prefetch survives).
// y1 = x @ w1_l (bf16 out), z1 = x @ w1_r (f32 out) via MFMA, 1-deep tile
// prefetch. Grid 1024 (more resident waves to cover L3-hit latency).
// ---------------------------------------------------------------------------
__global__ __launch_bounds__(256) void k_xform(const float* __restrict__ x,
                                               const float* __restrict__ w1l,
                                               const float* __restrict__ w1r,
                                               unsigned* __restrict__ y1b,
                                               float* __restrict__ z1, int N) {
    const int lane = threadIdx.x & 63;
    const int m    = lane & 15;
    const int quad = lane >> 4;
    const int wid  = (int)((blockIdx.x * 256 + threadIdx.x) >> 6);
    const int nw   = (int)((gridDim.x * 256) >> 6);
    const int ntiles = N >> 4;

    bf16x8 AL[4], AR[4];
#pragma unroll
    for (int kk = 0; kk < 4; ++kk) {
        union { unsigned u[4]; bf16x8 v; } al, ar;
#pragma unroll
        for (int p = 0; p < 4; ++p) {
            int d0 = kk * 32 + quad * 8 + 2 * p;
            al.u[p] = pack2(w1l[(size_t)d0 * HH + m], w1l[(size_t)(d0 + 1) * HH + m]);
            ar.u[p] = pack2(w1r[(size_t)d0 * HH + m], w1r[(size_t)(d0 + 1) * HH + m]);
        }
        AL[kk] = al.v; AR[kk] = ar.v;
    }

    const float4* xg = (const float4*)x;
    int tile = wid;
    if (tile < ntiles) {
        float4 cx[8];
#pragma unroll
        for (int kk = 0; kk < 4; ++kk) {
            size_t o = (size_t)(tile * 16 + m) * 32 + kk * 8 + quad * 2;
            cx[kk * 2]     = xg[o];
            cx[kk * 2 + 1] = xg[o + 1];
        }
        while (tile < ntiles) {
            int ntile = tile + nw;
            float4 nx[8];
            if (ntile < ntiles) {
#pragma unroll
                for (int kk = 0; kk < 4; ++kk) {
                    size_t o = (size_t)(ntile * 16 + m) * 32 + kk * 8 + quad * 2;
                    nx[kk * 2]     = xg[o];
                    nx[kk * 2 + 1] = xg[o + 1];
                }
            }
            f32x4 accL = {0.f, 0.f, 0.f, 0.f};
            f32x4 accR = {0.f, 0.f, 0.f, 0.f};
#pragma unroll
            for (int kk = 0; kk < 4; ++kk) {
                union { unsigned u[4]; bf16x8 v; } bx;
                float4 a = cx[kk * 2], b = cx[kk * 2 + 1];
                bx.u[0] = pack2(a.x, a.y);
                bx.u[1] = pack2(a.z, a.w);
                bx.u[2] = pack2(b.x, b.y);
                bx.u[3] = pack2(b.z, b.w);
                accL = __builtin_amdgcn_mfma_f32_16x16x32_bf16(AL[kk], bx.v, accL, 0, 0, 0);
                accR = __builtin_amdgcn_mfma_f32_16x16x32_bf16(AR[kk], bx.v, accR, 0, 0, 0);
            }
            int row = tile * 16 + m;
            uint2 yp; yp.x = pack2(accL[0], accL[1]); yp.y = pack2(accL[2], accL[3]);
            ((uint2*)y1b)[(size_t)row * 4 + quad] = yp;
            float4 zf = {accR[0], accR[1], accR[2], accR[3]};
            ((float4*)z1)[(size_t)row * 4 + quad] = zf;
            tile = ntile;
#pragma unroll
            for (int i = 0; i < 8; ++i) cx[i] = nx[i];
        }
    }

    // scalar tail for N % 16 (not hit when N % 16 == 0)
    const int tail0 = ntiles << 4;
    if (tail0 < N && blockIdx.x == 0) {
        for (int idx = threadIdx.x; idx < (N - tail0) * HH; idx += 256) {
            int row = tail0 + (idx >> 4), n = idx & 15;
            float sl = 0.f, sr = 0.f;
            for (int d = 0; d < DD; ++d) {
                float xv = x[(size_t)row * DD + d];
                sl += xv * w1l[(size_t)d * HH + n];
                sr += xv * w1r[(size_t)d * HH + n];
            }
            ((unsigned short*)y1b)[(size_t)row * 16 + n] = (unsigned short)b16(sl);
            z1[(size_t)row * HH + n] = sr;
        }
    }
}

// ---------------------------------------------------------------------------
// K5: one block per bucket (gapped layout).
//   Phase A: LDS counting sort, write nodestart/ncnt/csr.
//   Phase B: 8 lanes/node: sg = sub&1 picks the 16B half of the 32B y-row,
//            eh = sub>>1 is a 4-way edge split. Each lane gathers uint4
//            (16 B) per edge — adjacent sg lanes cover a full row (coalesced
//            32 B). eh-reduce via shfl_xor(2,8)/(4,8); then h = relu(mean +
//            b1 + z1) on 8 components and classifier collapse with the
//            sg-half of u_s/r_s; sg-reduce via shfl_xor(1,2); lanes 0/1
//            write the q/p planes.
// ---------------------------------------------------------------------------
__global__ __launch_bounds__(256) void k_sortagg(const int* __restrict__ packed,
                                                 const int* __restrict__ bcnt,
                                                 int* __restrict__ nodestart,
                                                 int* __restrict__ ncnt,
                                                 int* __restrict__ csr,
                                                 const unsigned* __restrict__ y1b,
                                                 const float* __restrict__ z1,
                                                 const float* __restrict__ b1,
                                                 const float* __restrict__ wsu,
                                                 float* __restrict__ qarr,
                                                 float* __restrict__ parr,
                                                 int N) {
    __shared__ int buf[SCAP];
    __shared__ int sbuf[SCAP];
    __shared__ int hist[BW];
    __shared__ int exs[BW];
    __shared__ int curs[BW];
    __shared__ int wtot;
    const int tid = threadIdx.x;
    const int b = blockIdx.x;
    const int st = b << 12;                 // gapped base
    int cnt = bcnt[b];
    if (cnt > SCAP) cnt = SCAP;             // never hit (max ~2300); defensive

    if (tid < BW) hist[tid] = 0;
    __syncthreads();
    for (int i = tid; i < cnt; i += 256) {
        int e = packed[st + i];
        buf[i] = e;
        atomicAdd(&hist[e >> 20], 1);
    }
    __syncthreads();

    int v = 0, s = 0;
    if (tid < BW) {
        int lane = tid & 63;
        v = hist[tid];
        s = v;
#pragma unroll
        for (int off = 1; off < 64; off <<= 1) {
            int u = __shfl_up(s, off, 64);
            if (lane >= off) s += u;
        }
        if (tid == 63) wtot = s;
    }
    __syncthreads();
    if (tid < BW) {
        int ex = s - v + ((tid >= 64) ? wtot : 0);
        exs[tid] = ex;
        curs[tid] = ex;
        int node = (b << 7) + tid;
        if (node < N) { nodestart[node] = st + ex; ncnt[node] = v; }
    }
    __syncthreads();

    for (int i = tid; i < cnt; i += 256) {
        int e = buf[i];
        int p = atomicAdd(&curs[e >> 20], 1);
        sbuf[p] = e & 0xFFFFF;
    }
    __syncthreads();
    for (int i = tid; i < cnt; i += 256) csr[st + i] = sbuf[i];  // coalesced

    // ---- Phase B: 8 lanes/node, 4 quarters of 32 nodes ----
    const uint4* f4 = (const uint4*)y1b;
    const int sub = tid & 7;
    const int sg  = sub & 1;       // 16B half of 32B y-row
    const int eh  = sub >> 1;      // 0..3 edge phase
    const float4* wsu4 = (const float4*)wsu;
    const float4 U0a = wsu4[sg * 2],      U0b = wsu4[sg * 2 + 1];       // u_0
    const float4 U1a = wsu4[4 + sg * 2],  U1b = wsu4[4 + sg * 2 + 1];   // u_1
    const float4 U2a = wsu4[8 + sg * 2],  U2b = wsu4[8 + sg * 2 + 1];   // r_0
    const float4 U3a = wsu4[12 + sg * 2], U3b = wsu4[12 + sg * 2 + 1];  // r_1
#pragma unroll
    for (int qtr = 0; qtr < 4; ++qtr) {
        int l = (tid >> 3) + qtr * 32;
        int node = (b << 7) + l;
        if (node < N) {
            int s0 = exs[l], c = hist[l];
            float a0 = 0.f, a1 = 0.f, a2 = 0.f, a3 = 0.f;
            float a4 = 0.f, a5 = 0.f, a6 = 0.f, a7 = 0.f;
            for (int k = eh; k < c; k += 4) {
                uint4 yv = f4[(size_t)(sbuf[s0 + k] * 2 + sg)];
                a0 += lo16(yv.x); a1 += hi16(yv.x);
                a2 += lo16(yv.y); a3 += hi16(yv.y);
                a4 += lo16(yv.z); a5 += hi16(yv.z);
                a6 += lo16(yv.w); a7 += hi16(yv.w);
            }
            // reduce over eh (bits 1,2 of sub)
            a0 += __shfl_xor(a0, 2, 8); a1 += __shfl_xor(a1, 2, 8);
            a2 += __shfl_xor(a2, 2, 8); a3 += __shfl_xor(a3, 2, 8);
            a4 += __shfl_xor(a4, 2, 8); a5 += __shfl_xor(a5, 2, 8);
            a6 += __shfl_xor(a6, 2, 8); a7 += __shfl_xor(a7, 2, 8);
            a0 += __shfl_xor(a0, 4, 8); a1 += __shfl_xor(a1, 4, 8);
            a2 += __shfl_xor(a2, 4, 8); a3 += __shfl_xor(a3, 4, 8);
            a4 += __shfl_xor(a4, 4, 8); a5 += __shfl_xor(a5, 4, 8);
            a6 += __shfl_xor(a6, 4, 8); a7 += __shfl_xor(a7, 4, 8);
            // lanes sub==0 (sg 0) and sub==1 (sg 1) hold full half-sums
            float d0 = 0.f, d1 = 0.f, d2 = 0.f, d3 = 0.f;
            if (eh == 0) {
                float inv = 1.f / fmaxf((float)c, 1.f);
                const float4* z4 = (const float4*)z1;   // 16 f32/row
                float4 zA = z4[(size_t)node * 4 + sg * 2];
                float4 zB = z4[(size_t)node * 4 + sg * 2 + 1];
                const float4* b4 = (const float4*)b1;
                float4 bA = b4[sg * 2], bB = b4[sg * 2 + 1];
                float h0 = fmaxf(a0 * inv + bA.x + zA.x, 0.f);
                float h1 = fmaxf(a1 * inv + bA.y + zA.y, 0.f);
                float h2 = fmaxf(a2 * inv + bA.z + zA.z, 0.f);
                float h3 = fmaxf(a3 * inv + bA.w + zA.w, 0.f);
                float h4 = fmaxf(a4 * inv + bB.x + zB.x, 0.f);
                float h5 = fmaxf(a5 * inv + bB.y + zB.y, 0.f);
                float h6 = fmaxf(a6 * inv + bB.z + zB.z, 0.f);
                float h7 = fmaxf(a7 * inv + bB.w + zB.w, 0.f);
                d0 = h0 * U0a.x + h1 * U0a.y + h2 * U0a.z + h3 * U0a.w
                   + h4 * U0b.x + h5 * U0b.y + h6 * U0b.z + h7 * U0b.w;
                d1 = h0 * U1a.x + h1 * U1a.y + h2 * U1a.z + h3 * U1a.w
                   + h4 * U1b.x + h5 * U1b.y + h6 * U1b.z + h7 * U1b.w;
                d2 = h0 * U2a.x + h1 * U2a.y + h2 * U2a.z + h3 * U2a.w
                   + h4 * U2b.x + h5 * U2b.y + h6 * U2b.z + h7 * U2b.w;
                d3 = h0 * U3a.x + h1 * U3a.y + h2 * U3a.z + h3 * U3a.w
                   + h4 * U3b.x + h5 * U3b.y + h6 * U3b.z + h7 * U3b.w;
            }
            // sum the two sg halves (lanes sub 0 <-> 1)
            d0 += __shfl_xor(d0, 1, 2);
            d1 += __shfl_xor(d1, 1, 2);
            d2 += __shfl_xor(d2, 1, 2);
            d3 += __shfl_xor(d3, 1, 2);
            if (sub == 0) { qarr[node] = d0; parr[node] = d2; }
            else if (sub == 1) { qarr[(size_t)N + node] = d1; parr[(size_t)N + node] = d3; }
        }
    }
}

// ---------------------------------------------------------------------------
// K6: pair logits + BCE from collapsed scalars. 8 lanes/pair:
// s = sub>>2 (article slot), part = sub&3 (edge 4-way split).
// ---------------------------------------------------------------------------
__global__ __launch_bounds__(256) void k_pair(const float* __restrict__ qarr,
                                              const float* __restrict__ parr,
                                              const int* __restrict__ csr,
                                              const int* __restrict__ nodestart,
                                              const int* __restrict__ ncnt,
                                              const int* __restrict__ a1,
                                              const int* __restrict__ a2,
                                              const int* __restrict__ labels,
                                              const float* __restrict__ wsu,
                                              float* __restrict__ out_logits,
                                              float* __restrict__ lacc,
                                              int* __restrict__ ticket,
                                              float* __restrict__ out0,
                                              int B, float invB, int N) {
    __shared__ float lred[4];
    int t = blockIdx.x * 256 + threadIdx.x;
    int pid = t >> 3, sub = t & 7;
    int s = sub >> 2, part = sub & 3;

    float hsum = 0.f;
    if (pid < B) {
        int node = s ? a2[pid] : a1[pid];
        int st = nodestart[node];
        int c = ncnt[node];
        const float* qs = qarr + (size_t)s * N;
        const int* ids = csr + st;
        float acc = 0.f;
        int k = part;
        for (; k + 4 < c; k += 8) {              // this lane: edges k, k+4
            int n0 = ids[k], n1 = ids[k + 4];
            acc += qs[n0] + qs[n1];
        }
        if (k < c) acc += qs[ids[k]];
        acc += __shfl_xor(acc, 1, 4);
        acc += __shfl_xor(acc, 2, 4);
        hsum = acc / fmaxf((float)c, 1.f) + parr[(size_t)s * N + node];
    }
    float other = __shfl_xor(hsum, 4, 8);
    float myloss = 0.f;
    if (pid < B && sub == 0) {
        float l = hsum + other + wsu[64] + wsu[65];
        out_logits[pid] = l;
        float y = (float)labels[pid];
        myloss = fmaxf(l, 0.f) - l * y + log1pf(expf(-fabsf(l)));
    }
    // block loss reduction
    float v = myloss;
#pragma unroll
    for (int off = 32; off; off >>= 1) v += __shfl_down(v, off, 64);
    if ((threadIdx.x & 63) == 0) lred[threadIdx.x >> 6] = v;
    __syncthreads();
    if (threadIdx.x == 0) {
        float ssum = lred[0] + lred[1] + lred[2] + lred[3];
        atomicAdd(lacc, ssum);
        __threadfence();
        int tk = atomicAdd(ticket, 1);
        if (tk == (int)gridDim.x - 1) {
            __threadfence();
            float total = atomicAdd(lacc, 0.f);
            out0[0] = total * invB;
        }
    }
}

// ---------------------------------------------------------------------------
extern "C" void kernel_launch(void* const* d_in, const int* in_sizes, int n_in,
                              void* d_out, int out_size, void* d_ws, size_t ws_size,
                              hipStream_t stream) {
    const float* x    = (const float*)d_in[0];
    const float* w1l  = (const float*)d_in[1];
    const float* b1   = (const float*)d_in[2];
    const float* w1r  = (const float*)d_in[3];
    const float* w2l  = (const float*)d_in[4];
    const float* b2v  = (const float*)d_in[5];
    const float* w2r  = (const float*)d_in[6];
    const float* wc   = (const float*)d_in[7];
    const float* bc   = (const float*)d_in[8];
    const int*   ei   = (const int*)d_in[9];
    const int*   a1   = (const int*)d_in[10];
    const int*   a2   = (const int*)d_in[11];
    const int*   lab  = (const int*)d_in[12];

    const int N = in_sizes[0] / DD;
    const int E = in_sizes[9] / 2;
    const int B = in_sizes[10];
    const int NB = (N + BW - 1) / BW;       // 782 for N=100000 (needs N < 2^20)

    const int* src = ei;
    const int* dst = ei + E;

    // workspace layout
    char* ws = (char*)d_ws;
    const size_t PSZ = (size_t)NB * GAPB * 4;                 // gapped packed/csr bytes
    float*    wsu    = (float*)ws;                            // 512 B
    unsigned* y1b    = (unsigned*)(ws + 512);                 // [N,16] bf16 (32 B/row)
    float*    z1     = (float*)   (ws + 512 + (size_t)N * 32);// [N,16] f32
    int*      packed = (int*)     (ws + 512 + (size_t)N * 96);
    int*      csr    = (int*)     (ws + 512 + (size_t)N * 96 + PSZ);
    char*     p4     = ws + 512 + (size_t)N * 96 + 2 * PSZ;
    int*   nodest  = (int*)p4;                               // [N]
    int*   ncnt    = (int*)(p4 + (size_t)N * 4);             // [N]
    float* qarr    = (float*)(p4 + (size_t)N * 8);           // [2N] planes q0,q1
    float* parr    = (float*)(p4 + (size_t)N * 16);          // [2N] planes p0,p1
    int*   bcnt    = (int*)(p4 + (size_t)N * 24);            // [NB] zeroed
    float* lacc    = (float*)(p4 + (size_t)N * 24 + (size_t)NB * 4);  // zeroed
    int*   ticket  = (int*)((char*)lacc + 4);                // zeroed

    float* out = (float*)d_out;       // out[0] = loss, out[1..B] = logits

    hipMemsetAsync((void*)bcnt, 0, (size_t)NB * 4 + 8, stream);

    const int E4 = E / 4;
    const int cblocks = (E4 + 511) / 512;            // 2048 edges per chunk

    k_scat<<<cblocks + 1, 256, 0, stream>>>(src, dst, bcnt, packed,
                                            E4, NB, cblocks,
                                            w2l, w2r, b2v, wc, bc, wsu);

    k_xform<<<XG, 256, 0, stream>>>(x, w1l, w1r, y1b, z1, N);

    k_sortagg<<<NB, 256, 0, stream>>>(packed, bcnt, nodest, ncnt, csr,
                                      y1b, z1, b1, wsu, qarr, parr, N);

    k_pair<<<(B * 8 + 255) / 256, 256, 0, stream>>>(qarr, parr, csr, nodest, ncnt,
                                                    a1, a2, lab, wsu,
                                                    out + 1, lacc, ticket, out,
                                                    B, 1.0f / (float)B, N);
}

// Round 9
// 190.918 us; speedup vs baseline: 1.0284x; 1.0284x over previous
//
#include <hip/hip_runtime.h>
#include <hip/hip_bf16.h>

#define DD 128    // feature dim
#define HH 16     // hidden dim
#define BW 128    // bucket width (nodes per bucket) = 1<<7
#define NBMAX 1024
#define GAPB 4096      // fixed per-bucket slot capacity (8 sub-slots of 512)
#define SCAP 4096      // LDS slice cap in sortagg
#define XG 512         // xform grid (1024 regresses +20us — replicated R1/R7)

// bf16x2 pack/unpack (RNE)
__device__ __forceinline__ float lo16(unsigned u) { return __uint_as_float(u << 16); }
__device__ __forceinline__ float hi16(unsigned u) { return __uint_as_float(u & 0xffff0000u); }
__device__ __forceinline__ unsigned b16(float f) {
    unsigned u = __float_as_uint(f);
    return (u + 0x7fffu + ((u >> 16) & 1u)) >> 16;
}
__device__ __forceinline__ unsigned pack2(float a, float b) {
    return b16(a) | (b16(b) << 16);
}

typedef __attribute__((ext_vector_type(8))) short bf16x8;   // MFMA A/B frag (4 VGPRs)
typedef __attribute__((ext_vector_type(4))) float f32x4;    // MFMA C/D frag

// ---------------------------------------------------------------------------
// K1 (k_scat): gapped-bucket single-pass scatter with XCD-PRIVATE sub-slots.
// Each bucket's 4096-slot gap region is split into 8 sub-slots of 512;
// a block writes only sub-slot g = bid&7 (XCD proxy under round-robin
// dispatch). All writes to a 64B line then come from ONE XCD's L2 ->
// lines fill locally and write back once (R7 measured 2.5x write
// amplification from cross-XCD partial-line dirties: 32MB HBM writes for a
// 12.8MB footprint). Reservation: (b<<12)+(g<<9)+atomicAdd(&bcnt8[b*8+g],h).
// Block cblocks does the classifier-collapse prep (wsu[0..65]).
// ---------------------------------------------------------------------------
__global__ __launch_bounds__(256) void k_scat(const int* __restrict__ src,
                                              const int* __restrict__ dst,
                                              int* __restrict__ bcnt8,
                                              int* __restrict__ packed,
                                              int E4, int NB, int cblocks,
                                              const float* __restrict__ w2l,
                                              const float* __restrict__ w2r,
                                              const float* __restrict__ b2v,
                                              const float* __restrict__ wc,
                                              const float* __restrict__ bc,
                                              float* __restrict__ wsu) {
    const int tid = threadIdx.x;
    const int bid = (int)blockIdx.x;

    if (bid == cblocks) {      // ---- prep block ----
        if (tid < 64) {
            int k = tid >> 4, j = tid & 15;
            const float* W = (k < 2) ? w2l : w2r;
            int off = (k & 1) * DD;
            float s = 0.f;
            for (int d = 0; d < DD; ++d) s += W[j * DD + d] * wc[off + d];
            wsu[k * 16 + j] = s;
        } else if (tid == 64) {
            float s = bc[0];
            for (int d = 0; d < DD; ++d) s += b2v[d] * wc[d];
            wsu[64] = s;
        } else if (tid == 65) {
            float s = 0.f;
            for (int d = 0; d < DD; ++d) s += b2v[d] * wc[DD + d];
            wsu[65] = s;
        }
        return;
    }

    const int g = bid & 7;                    // XCD proxy
    __shared__ int hist[NBMAX];
    __shared__ int cur[NBMAX];
    for (int i = tid; i < NB; i += 256) hist[i] = 0;
    __syncthreads();
    int base = bid * 1024;                    // int4 units: 4096 edges/block
    int4 dreg[4];
#pragma unroll
    for (int k = 0; k < 4; ++k) {
        int i4 = base + k * 256 + tid;
        if (i4 < E4) {
            int4 d = ((const int4*)dst)[i4];
            dreg[k] = d;
            atomicAdd(&hist[d.x >> 7], 1);
            atomicAdd(&hist[d.y >> 7], 1);
            atomicAdd(&hist[d.z >> 7], 1);
            atomicAdd(&hist[d.w >> 7], 1);
        }
    }
    __syncthreads();
    // reserve per-(bucket, xcd) ranges in the gapped global layout
    for (int i = tid; i < NB; i += 256) {
        int hv = hist[i];
        cur[i] = hv ? (i << 12) + (g << 9) + atomicAdd(&bcnt8[i * 8 + g], hv) : 0;
    }
    __syncthreads();
#pragma unroll
    for (int k = 0; k < 4; ++k) {
        int i4 = base + k * 256 + tid;
        if (i4 < E4) {
            int4 sv = ((const int4*)src)[i4];
            int4 d = dreg[k];
            int p;
            p = atomicAdd(&cur[d.x >> 7], 1); packed[p] = ((d.x & 127) << 20) | sv.x;
            p = atomicAdd(&cur[d.y >> 7], 1); packed[p] = ((d.y & 127) << 20) | sv.y;
            p = atomicAdd(&cur[d.z >> 7], 1); packed[p] = ((d.z & 127) << 20) | sv.z;
            p = atomicAdd(&cur[d.w >> 7], 1); packed[p] = ((d.w & 127) << 20) | sv.w;
        }
    }
}

// ---------------------------------------------------------------------------
// K4 (k_xform): standalone (own regalloc -> prefetch survives).
// y1 = x @ w1_l (bf16 out), z1 = x @ w1_r (f32 out) via MFMA, 1-deep tile
// prefetch. Grid 512 (1024 measured +20us twice — do not raise).
// ---------------------------------------------------------------------------
__global__ __launch_bounds__(256) void k_xform(const float* __restrict__ x,
                                               const float* __restrict__ w1l,
                                               const float* __restrict__ w1r,
                                               unsigned* __restrict__ y1b,
                                               float* __restrict__ z1, int N) {
    const int lane = threadIdx.x & 63;
    const int m    = lane & 15;
    const int quad = lane >> 4;
    const int wid  = (int)((blockIdx.x * 256 + threadIdx.x) >> 6);
    const int nw   = (int)((gridDim.x * 256) >> 6);
    const int ntiles = N >> 4;

    bf16x8 AL[4], AR[4];
#pragma unroll
    for (int kk = 0; kk < 4; ++kk) {
        union { unsigned u[4]; bf16x8 v; } al, ar;
#pragma unroll
        for (int p = 0; p < 4; ++p) {
            int d0 = kk * 32 + quad * 8 + 2 * p;
            al.u[p] = pack2(w1l[(size_t)d0 * HH + m], w1l[(size_t)(d0 + 1) * HH + m]);
            ar.u[p] = pack2(w1r[(size_t)d0 * HH + m], w1r[(size_t)(d0 + 1) * HH + m]);
        }
        AL[kk] = al.v; AR[kk] = ar.v;
    }

    const float4* xg = (const float4*)x;
    int tile = wid;
    if (tile < ntiles) {
        float4 cx[8];
#pragma unroll
        for (int kk = 0; kk < 4; ++kk) {
            size_t o = (size_t)(tile * 16 + m) * 32 + kk * 8 + quad * 2;
            cx[kk * 2]     = xg[o];
            cx[kk * 2 + 1] = xg[o + 1];
        }
        while (tile < ntiles) {
            int ntile = tile + nw;
            float4 nx[8];
            if (ntile < ntiles) {
#pragma unroll
                for (int kk = 0; kk < 4; ++kk) {
                    size_t o = (size_t)(ntile * 16 + m) * 32 + kk * 8 + quad * 2;
                    nx[kk * 2]     = xg[o];
                    nx[kk * 2 + 1] = xg[o + 1];
                }
            }
            f32x4 accL = {0.f, 0.f, 0.f, 0.f};
            f32x4 accR = {0.f, 0.f, 0.f, 0.f};
#pragma unroll
            for (int kk = 0; kk < 4; ++kk) {
                union { unsigned u[4]; bf16x8 v; } bx;
                float4 a = cx[kk * 2], b = cx[kk * 2 + 1];
                bx.u[0] = pack2(a.x, a.y);
                bx.u[1] = pack2(a.z, a.w);
                bx.u[2] = pack2(b.x, b.y);
                bx.u[3] = pack2(b.z, b.w);
                accL = __builtin_amdgcn_mfma_f32_16x16x32_bf16(AL[kk], bx.v, accL, 0, 0, 0);
                accR = __builtin_amdgcn_mfma_f32_16x16x32_bf16(AR[kk], bx.v, accR, 0, 0, 0);
            }
            int row = tile * 16 + m;
            uint2 yp; yp.x = pack2(accL[0], accL[1]); yp.y = pack2(accL[2], accL[3]);
            ((uint2*)y1b)[(size_t)row * 4 + quad] = yp;
            float4 zf = {accR[0], accR[1], accR[2], accR[3]};
            ((float4*)z1)[(size_t)row * 4 + quad] = zf;
            tile = ntile;
#pragma unroll
            for (int i = 0; i < 8; ++i) cx[i] = nx[i];
        }
    }

    // scalar tail for N % 16 (not hit when N % 16 == 0)
    const int tail0 = ntiles << 4;
    if (tail0 < N && blockIdx.x == 0) {
        for (int idx = threadIdx.x; idx < (N - tail0) * HH; idx += 256) {
            int row = tail0 + (idx >> 4), n = idx & 15;
            float sl = 0.f, sr = 0.f;
            for (int d = 0; d < DD; ++d) {
                float xv = x[(size_t)row * DD + d];
                sl += xv * w1l[(size_t)d * HH + n];
                sr += xv * w1r[(size_t)d * HH + n];
            }
            ((unsigned short*)y1b)[(size_t)row * 16 + n] = (unsigned short)b16(sl);
            z1[(size_t)row * HH + n] = sr;
        }
    }
}

// ---------------------------------------------------------------------------
// K5: one block per bucket. The bucket slice now lives in 8 XCD sub-runs:
// run g at [(b<<12)+(g<<9), +bcnt8[b*8+g]). Concatenate runs into LDS
// (coalesced reads), then LDS counting sort + phase B as before.
// ---------------------------------------------------------------------------
__global__ __launch_bounds__(256) void k_sortagg(const int* __restrict__ packed,
                                                 const int* __restrict__ bcnt8,
                                                 int* __restrict__ nodestart,
                                                 int* __restrict__ ncnt,
                                                 int* __restrict__ csr,
                                                 const unsigned* __restrict__ y1b,
                                                 const float* __restrict__ z1,
                                                 const float* __restrict__ b1,
                                                 const float* __restrict__ wsu,
                                                 float* __restrict__ qarr,
                                                 float* __restrict__ parr,
                                                 int N) {
    __shared__ int buf[SCAP];
    __shared__ int sbuf[SCAP];
    __shared__ int hist[BW];
    __shared__ int exs[BW];
    __shared__ int curs[BW];
    __shared__ int wtot;
    __shared__ int goff[9];
    const int tid = threadIdx.x;
    const int b = blockIdx.x;
    const int st = b << 12;                 // gapped base

    if (tid == 0) {
        int acc = 0;
        goff[0] = 0;
#pragma unroll
        for (int gg = 0; gg < 8; ++gg) {
            acc += bcnt8[b * 8 + gg];
            goff[gg + 1] = acc;
        }
    }
    if (tid < BW) hist[tid] = 0;
    __syncthreads();
    int cnt = goff[8];
    if (cnt > SCAP) cnt = SCAP;             // never hit (max ~2300); defensive

    for (int i = tid; i < cnt; i += 256) {
        int g = 0;
#pragma unroll
        for (int gg = 1; gg < 8; ++gg) g += (i >= goff[gg]);
        int e = packed[st + (g << 9) + (i - goff[g])];
        buf[i] = e;
        atomicAdd(&hist[e >> 20], 1);
    }
    __syncthreads();

    int v = 0, s = 0;
    if (tid < BW) {
        int lane = tid & 63;
        v = hist[tid];
        s = v;
#pragma unroll
        for (int off = 1; off < 64; off <<= 1) {
            int u = __shfl_up(s, off, 64);
            if (lane >= off) s += u;
        }
        if (tid == 63) wtot = s;
    }
    __syncthreads();
    if (tid < BW) {
        int ex = s - v + ((tid >= 64) ? wtot : 0);
        exs[tid] = ex;
        curs[tid] = ex;
        int node = (b << 7) + tid;
        if (node < N) { nodestart[node] = st + ex; ncnt[node] = v; }
    }
    __syncthreads();

    for (int i = tid; i < cnt; i += 256) {
        int e = buf[i];
        int p = atomicAdd(&curs[e >> 20], 1);
        sbuf[p] = e & 0xFFFFF;
    }
    __syncthreads();
    for (int i = tid; i < cnt; i += 256) csr[st + i] = sbuf[i];  // coalesced

    // ---- Phase B: 8 lanes/node, 4 quarters of 32 nodes ----
    const uint4* f4 = (const uint4*)y1b;
    const int sub = tid & 7;
    const int sg  = sub & 1;       // 16B half of 32B y-row
    const int eh  = sub >> 1;      // 0..3 edge phase
    const float4* wsu4 = (const float4*)wsu;
    const float4 U0a = wsu4[sg * 2],      U0b = wsu4[sg * 2 + 1];       // u_0
    const float4 U1a = wsu4[4 + sg * 2],  U1b = wsu4[4 + sg * 2 + 1];   // u_1
    const float4 U2a = wsu4[8 + sg * 2],  U2b = wsu4[8 + sg * 2 + 1];   // r_0
    const float4 U3a = wsu4[12 + sg * 2], U3b = wsu4[12 + sg * 2 + 1];  // r_1
#pragma unroll
    for (int qtr = 0; qtr < 4; ++qtr) {
        int l = (tid >> 3) + qtr * 32;
        int node = (b << 7) + l;
        if (node < N) {
            int s0 = exs[l], c = hist[l];
            float a0 = 0.f, a1 = 0.f, a2 = 0.f, a3 = 0.f;
            float a4 = 0.f, a5 = 0.f, a6 = 0.f, a7 = 0.f;
            for (int k = eh; k < c; k += 4) {
                uint4 yv = f4[(size_t)(sbuf[s0 + k] * 2 + sg)];
                a0 += lo16(yv.x); a1 += hi16(yv.x);
                a2 += lo16(yv.y); a3 += hi16(yv.y);
                a4 += lo16(yv.z); a5 += hi16(yv.z);
                a6 += lo16(yv.w); a7 += hi16(yv.w);
            }
            // reduce over eh (bits 1,2 of sub)
            a0 += __shfl_xor(a0, 2, 8); a1 += __shfl_xor(a1, 2, 8);
            a2 += __shfl_xor(a2, 2, 8); a3 += __shfl_xor(a3, 2, 8);
            a4 += __shfl_xor(a4, 2, 8); a5 += __shfl_xor(a5, 2, 8);
            a6 += __shfl_xor(a6, 2, 8); a7 += __shfl_xor(a7, 2, 8);
            a0 += __shfl_xor(a0, 4, 8); a1 += __shfl_xor(a1, 4, 8);
            a2 += __shfl_xor(a2, 4, 8); a3 += __shfl_xor(a3, 4, 8);
            a4 += __shfl_xor(a4, 4, 8); a5 += __shfl_xor(a5, 4, 8);
            a6 += __shfl_xor(a6, 4, 8); a7 += __shfl_xor(a7, 4, 8);
            // lanes sub==0 (sg 0) and sub==1 (sg 1) hold full half-sums
            float d0 = 0.f, d1 = 0.f, d2 = 0.f, d3 = 0.f;
            if (eh == 0) {
                float inv = 1.f / fmaxf((float)c, 1.f);
                const float4* z4 = (const float4*)z1;   // 16 f32/row
                float4 zA = z4[(size_t)node * 4 + sg * 2];
                float4 zB = z4[(size_t)node * 4 + sg * 2 + 1];
                const float4* b4 = (const float4*)b1;
                float4 bA = b4[sg * 2], bB = b4[sg * 2 + 1];
                float h0 = fmaxf(a0 * inv + bA.x + zA.x, 0.f);
                float h1 = fmaxf(a1 * inv + bA.y + zA.y, 0.f);
                float h2 = fmaxf(a2 * inv + bA.z + zA.z, 0.f);
                float h3 = fmaxf(a3 * inv + bA.w + zA.w, 0.f);
                float h4 = fmaxf(a4 * inv + bB.x + zB.x, 0.f);
                float h5 = fmaxf(a5 * inv + bB.y + zB.y, 0.f);
                float h6 = fmaxf(a6 * inv + bB.z + zB.z, 0.f);
                float h7 = fmaxf(a7 * inv + bB.w + zB.w, 0.f);
                d0 = h0 * U0a.x + h1 * U0a.y + h2 * U0a.z + h3 * U0a.w
                   + h4 * U0b.x + h5 * U0b.y + h6 * U0b.z + h7 * U0b.w;
                d1 = h0 * U1a.x + h1 * U1a.y + h2 * U1a.z + h3 * U1a.w
                   + h4 * U1b.x + h5 * U1b.y + h6 * U1b.z + h7 * U1b.w;
                d2 = h0 * U2a.x + h1 * U2a.y + h2 * U2a.z + h3 * U2a.w
                   + h4 * U2b.x + h5 * U2b.y + h6 * U2b.z + h7 * U2b.w;
                d3 = h0 * U3a.x + h1 * U3a.y + h2 * U3a.z + h3 * U3a.w
                   + h4 * U3b.x + h5 * U3b.y + h6 * U3b.z + h7 * U3b.w;
            }
            // sum the two sg halves (lanes sub 0 <-> 1)
            d0 += __shfl_xor(d0, 1, 2);
            d1 += __shfl_xor(d1, 1, 2);
            d2 += __shfl_xor(d2, 1, 2);
            d3 += __shfl_xor(d3, 1, 2);
            if (sub == 0) { qarr[node] = d0; parr[node] = d2; }
            else if (sub == 1) { qarr[(size_t)N + node] = d1; parr[(size_t)N + node] = d3; }
        }
    }
}

// ---------------------------------------------------------------------------
// K6: pair logits + BCE from collapsed scalars. 8 lanes/pair:
// s = sub>>2 (article slot), part = sub&3 (edge 4-way split).
// ---------------------------------------------------------------------------
__global__ __launch_bounds__(256) void k_pair(const float* __restrict__ qarr,
                                              const float* __restrict__ parr,
                                              const int* __restrict__ csr,
                                              const int* __restrict__ nodestart,
                                              const int* __restrict__ ncnt,
                                              const int* __restrict__ a1,
                                              const int* __restrict__ a2,
                                              const int* __restrict__ labels,
                                              const float* __restrict__ wsu,
                                              float* __restrict__ out_logits,
                                              float* __restrict__ lacc,
                                              int* __restrict__ ticket,
                                              float* __restrict__ out0,
                                              int B, float invB, int N) {
    __shared__ float lred[4];
    int t = blockIdx.x * 256 + threadIdx.x;
    int pid = t >> 3, sub = t & 7;
    int s = sub >> 2, part = sub & 3;

    float hsum = 0.f;
    if (pid < B) {
        int node = s ? a2[pid] : a1[pid];
        int st = nodestart[node];
        int c = ncnt[node];
        const float* qs = qarr + (size_t)s * N;
        const int* ids = csr + st;
        float acc = 0.f;
        int k = part;
        for (; k + 4 < c; k += 8) {              // this lane: edges k, k+4
            int n0 = ids[k], n1 = ids[k + 4];
            acc += qs[n0] + qs[n1];
        }
        if (k < c) acc += qs[ids[k]];
        acc += __shfl_xor(acc, 1, 4);
        acc += __shfl_xor(acc, 2, 4);
        hsum = acc / fmaxf((float)c, 1.f) + parr[(size_t)s * N + node];
    }
    float other = __shfl_xor(hsum, 4, 8);
    float myloss = 0.f;
    if (pid < B && sub == 0) {
        float l = hsum + other + wsu[64] + wsu[65];
        out_logits[pid] = l;
        float y = (float)labels[pid];
        myloss = fmaxf(l, 0.f) - l * y + log1pf(expf(-fabsf(l)));
    }
    // block loss reduction
    float v = myloss;
#pragma unroll
    for (int off = 32; off; off >>= 1) v += __shfl_down(v, off, 64);
    if ((threadIdx.x & 63) == 0) lred[threadIdx.x >> 6] = v;
    __syncthreads();
    if (threadIdx.x == 0) {
        float ssum = lred[0] + lred[1] + lred[2] + lred[3];
        atomicAdd(lacc, ssum);
        __threadfence();
        int tk = atomicAdd(ticket, 1);
        if (tk == (int)gridDim.x - 1) {
            __threadfence();
            float total = atomicAdd(lacc, 0.f);
            out0[0] = total * invB;
        }
    }
}

// ---------------------------------------------------------------------------
extern "C" void kernel_launch(void* const* d_in, const int* in_sizes, int n_in,
                              void* d_out, int out_size, void* d_ws, size_t ws_size,
                              hipStream_t stream) {
    const float* x    = (const float*)d_in[0];
    const float* w1l  = (const float*)d_in[1];
    const float* b1   = (const float*)d_in[2];
    const float* w1r  = (const float*)d_in[3];
    const float* w2l  = (const float*)d_in[4];
    const float* b2v  = (const float*)d_in[5];
    const float* w2r  = (const float*)d_in[6];
    const float* wc   = (const float*)d_in[7];
    const float* bc   = (const float*)d_in[8];
    const int*   ei   = (const int*)d_in[9];
    const int*   a1   = (const int*)d_in[10];
    const int*   a2   = (const int*)d_in[11];
    const int*   lab  = (const int*)d_in[12];

    const int N = in_sizes[0] / DD;
    const int E = in_sizes[9] / 2;
    const int B = in_sizes[10];
    const int NB = (N + BW - 1) / BW;       // 782 for N=100000 (needs N < 2^20)

    const int* src = ei;
    const int* dst = ei + E;

    // workspace layout
    char* ws = (char*)d_ws;
    const size_t PSZ = (size_t)NB * GAPB * 4;                 // gapped packed/csr bytes
    float*    wsu    = (float*)ws;                            // 512 B
    unsigned* y1b    = (unsigned*)(ws + 512);                 // [N,16] bf16 (32 B/row)
    float*    z1     = (float*)   (ws + 512 + (size_t)N * 32);// [N,16] f32
    int*      packed = (int*)     (ws + 512 + (size_t)N * 96);
    int*      csr    = (int*)     (ws + 512 + (size_t)N * 96 + PSZ);
    char*     p4     = ws + 512 + (size_t)N * 96 + 2 * PSZ;
    int*   nodest  = (int*)p4;                               // [N]
    int*   ncnt    = (int*)(p4 + (size_t)N * 4);             // [N]
    float* qarr    = (float*)(p4 + (size_t)N * 8);           // [2N] planes q0,q1
    float* parr    = (float*)(p4 + (size_t)N * 16);          // [2N] planes p0,p1
    int*   bcnt8   = (int*)(p4 + (size_t)N * 24);            // [NB*8] zeroed
    float* lacc    = (float*)(p4 + (size_t)N * 24 + (size_t)NB * 32); // zeroed
    int*   ticket  = (int*)((char*)lacc + 4);                // zeroed

    float* out = (float*)d_out;       // out[0] = loss, out[1..B] = logits

    hipMemsetAsync((void*)bcnt8, 0, (size_t)NB * 32 + 8, stream);

    const int E4 = E / 4;
    const int cblocks = (E4 + 1023) / 1024;          // 4096 edges per chunk

    k_scat<<<cblocks + 1, 256, 0, stream>>>(src, dst, bcnt8, packed,
                                            E4, NB, cblocks,
                                            w2l, w2r, b2v, wc, bc, wsu);

    k_xform<<<XG, 256, 0, stream>>>(x, w1l, w1r, y1b, z1, N);

    k_sortagg<<<NB, 256, 0, stream>>>(packed, bcnt8, nodest, ncnt, csr,
                                      y1b, z1, b1, wsu, qarr, parr, N);

    k_pair<<<(B * 8 + 255) / 256, 256, 0, stream>>>(qarr, parr, csr, nodest, ncnt,
                                                    a1, a2, lab, wsu,
                                                    out + 1, lacc, ticket, out,
                                                    B, 1.0f / (float)B, N);
}

// Round 10
// 188.911 us; speedup vs baseline: 1.0394x; 1.0106x over previous
//
#include <hip/hip_runtime.h>
#include <hip/hip_bf16.h>

#define DD 128    // feature dim
#define HH 16     // hidden dim
#define BW 128    // bucket width (nodes per bucket) = 1<<7
#define NBMAX 1024
#define GAPB 4096      // per-bucket slot capacity (8 XCD sub-slots of 512)
#define SCAP 4096      // LDS slice cap in sortagg
#define XG 384         // xform blocks in k_front

// bf16x2 pack/unpack (RNE)
__device__ __forceinline__ float lo16(unsigned u) { return __uint_as_float(u << 16); }
__device__ __forceinline__ float hi16(unsigned u) { return __uint_as_float(u & 0xffff0000u); }
__device__ __forceinline__ unsigned b16(float f) {
    unsigned u = __float_as_uint(f);
    return (u + 0x7fffu + ((u >> 16) & 1u)) >> 16;
}
__device__ __forceinline__ unsigned pack2(float a, float b) {
    return b16(a) | (b16(b) << 16);
}

typedef __attribute__((ext_vector_type(8))) short bf16x8;   // MFMA A/B frag (4 VGPRs)
typedef __attribute__((ext_vector_type(4))) float f32x4;    // MFMA C/D frag

// ---------------------------------------------------------------------------
// K1 (k_front): the measured-best fused front (174.8us config) + XCD-subslot
// packing in the scat role. Three block roles:
//   [0, cblocks)  : gapped-bucket single-pass scatter, 4096 edges/block.
//                   Sub-slot g = bid&7 (XCD proxy under round-robin dispatch):
//                   packed[(b<<12)+(g<<9)+pos], pos from bcnt8[b*8+g]. All
//                   writes to a 64B line then come from one XCD's L2 (R7
//                   measured 5x write amplification without this).
//   cblocks       : classifier-collapse prep (wsu[0..65]).
//   (cblocks,+XG] : xform y1 = x@w1_l (bf16), z1 = x@w1_r (f32) via MFMA,
//                   single-buffered (load->pack->MFMA fused).
// ---------------------------------------------------------------------------
__global__ __launch_bounds__(256)
__attribute__((amdgpu_waves_per_eu(1, 4)))
void k_front(const int* __restrict__ src,
             const int* __restrict__ dst,
             int* __restrict__ bcnt8,
             int* __restrict__ packed,
             int E4, int NB, int cblocks,
             const float* __restrict__ w2l,
             const float* __restrict__ w2r,
             const float* __restrict__ b2v,
             const float* __restrict__ wc,
             const float* __restrict__ bc,
             float* __restrict__ wsu,
             const float* __restrict__ x,
             const float* __restrict__ w1l,
             const float* __restrict__ w1r,
             unsigned* __restrict__ y1b,
             float* __restrict__ z1, int N) {
    const int tid = threadIdx.x;
    const int bid = (int)blockIdx.x;

    if (bid == cblocks) {      // ---- prep block ----
        if (tid < 64) {
            int k = tid >> 4, j = tid & 15;
            const float* W = (k < 2) ? w2l : w2r;
            int off = (k & 1) * DD;
            float s = 0.f;
            for (int d = 0; d < DD; ++d) s += W[j * DD + d] * wc[off + d];
            wsu[k * 16 + j] = s;
        } else if (tid == 64) {
            float s = bc[0];
            for (int d = 0; d < DD; ++d) s += b2v[d] * wc[d];
            wsu[64] = s;
        } else if (tid == 65) {
            float s = 0.f;
            for (int d = 0; d < DD; ++d) s += b2v[d] * wc[DD + d];
            wsu[65] = s;
        }
        return;
    }

    if (bid > cblocks) {       // ---- xform blocks (single-buffered, reg-light) ----
        const int xb   = bid - cblocks - 1;          // 0..XG-1
        const int lane = tid & 63;
        const int m    = lane & 15;
        const int quad = lane >> 4;
        const int nw   = XG * 4;                     // total xform waves
        const int wid  = xb * 4 + (tid >> 6);
        const int ntiles = N >> 4;

        bf16x8 AL[4], AR[4];
#pragma unroll
        for (int kk = 0; kk < 4; ++kk) {
            union { unsigned u[4]; bf16x8 v; } al, ar;
#pragma unroll
            for (int p = 0; p < 4; ++p) {
                int d0 = kk * 32 + quad * 8 + 2 * p;
                al.u[p] = pack2(w1l[(size_t)d0 * HH + m], w1l[(size_t)(d0 + 1) * HH + m]);
                ar.u[p] = pack2(w1r[(size_t)d0 * HH + m], w1r[(size_t)(d0 + 1) * HH + m]);
            }
            AL[kk] = al.v; AR[kk] = ar.v;
        }

        const float4* xg4 = (const float4*)x;
        for (int tile = wid; tile < ntiles; tile += nw) {
            f32x4 accL = {0.f, 0.f, 0.f, 0.f};
            f32x4 accR = {0.f, 0.f, 0.f, 0.f};
#pragma unroll
            for (int kk = 0; kk < 4; ++kk) {
                size_t o = (size_t)(tile * 16 + m) * 32 + kk * 8 + quad * 2;
                float4 a = xg4[o], b = xg4[o + 1];
                union { unsigned u[4]; bf16x8 v; } bx;
                bx.u[0] = pack2(a.x, a.y);
                bx.u[1] = pack2(a.z, a.w);
                bx.u[2] = pack2(b.x, b.y);
                bx.u[3] = pack2(b.z, b.w);
                accL = __builtin_amdgcn_mfma_f32_16x16x32_bf16(AL[kk], bx.v, accL, 0, 0, 0);
                accR = __builtin_amdgcn_mfma_f32_16x16x32_bf16(AR[kk], bx.v, accR, 0, 0, 0);
            }
            int row = tile * 16 + m;
            uint2 yp; yp.x = pack2(accL[0], accL[1]); yp.y = pack2(accL[2], accL[3]);
            ((uint2*)y1b)[(size_t)row * 4 + quad] = yp;
            float4 zf = {accR[0], accR[1], accR[2], accR[3]};
            ((float4*)z1)[(size_t)row * 4 + quad] = zf;
        }

        // scalar tail for N % 16 (not hit when N % 16 == 0)
        const int tail0 = ntiles << 4;
        if (tail0 < N && xb == 0) {
            for (int idx = tid; idx < (N - tail0) * HH; idx += 256) {
                int row = tail0 + (idx >> 4), n = idx & 15;
                float sl = 0.f, sr = 0.f;
                for (int d = 0; d < DD; ++d) {
                    float xv = x[(size_t)row * DD + d];
                    sl += xv * w1l[(size_t)d * HH + n];
                    sr += xv * w1r[(size_t)d * HH + n];
                }
                ((unsigned short*)y1b)[(size_t)row * 16 + n] = (unsigned short)b16(sl);
                z1[(size_t)row * HH + n] = sr;
            }
        }
        return;
    }

    // ---- scat blocks: gapped-bucket scatter into XCD-private sub-slots ----
    const int g = bid & 7;                    // XCD proxy
    __shared__ int hist[NBMAX];
    __shared__ int cur[NBMAX];
    for (int i = tid; i < NB; i += 256) hist[i] = 0;
    __syncthreads();
    int base = bid * 1024;
    int4 dreg[4];
#pragma unroll
    for (int k = 0; k < 4; ++k) {
        int i4 = base + k * 256 + tid;
        if (i4 < E4) {
            int4 d = ((const int4*)dst)[i4];
            dreg[k] = d;
            atomicAdd(&hist[d.x >> 7], 1);
            atomicAdd(&hist[d.y >> 7], 1);
            atomicAdd(&hist[d.z >> 7], 1);
            atomicAdd(&hist[d.w >> 7], 1);
        }
    }
    __syncthreads();
    for (int i = tid; i < NB; i += 256) {
        int hv = hist[i];
        cur[i] = hv ? (i << 12) + (g << 9) + atomicAdd(&bcnt8[i * 8 + g], hv) : 0;
    }
    __syncthreads();
#pragma unroll
    for (int k = 0; k < 4; ++k) {
        int i4 = base + k * 256 + tid;
        if (i4 < E4) {
            int4 sv = ((const int4*)src)[i4];
            int4 d = dreg[k];
            int p;
            p = atomicAdd(&cur[d.x >> 7], 1); packed[p] = ((d.x & 127) << 20) | sv.x;
            p = atomicAdd(&cur[d.y >> 7], 1); packed[p] = ((d.y & 127) << 20) | sv.y;
            p = atomicAdd(&cur[d.z >> 7], 1); packed[p] = ((d.z & 127) << 20) | sv.z;
            p = atomicAdd(&cur[d.w >> 7], 1); packed[p] = ((d.w & 127) << 20) | sv.w;
        }
    }
}

// ---------------------------------------------------------------------------
// K5: one block per bucket. Bucket slice lives in 8 XCD sub-runs:
// run g at [(b<<12)+(g<<9), +bcnt8[b*8+g]). Phase A concatenates runs into
// LDS (coalesced), then counting-sorts; writes nodestart/ncnt/csr.
// Phase B (the measured-best 4-lane uint2 form): layer-1 mean ->
// h = relu(mean + b1 + z1) in registers -> classifier collapse
// q_s = h.u_s, p_s = h.r_s -> scalar planes.
// ---------------------------------------------------------------------------
__global__ __launch_bounds__(256) void k_sortagg(const int* __restrict__ packed,
                                                 const int* __restrict__ bcnt8,
                                                 int* __restrict__ nodestart,
                                                 int* __restrict__ ncnt,
                                                 int* __restrict__ csr,
                                                 const unsigned* __restrict__ y1b,
                                                 const float* __restrict__ z1,
                                                 const float* __restrict__ b1,
                                                 const float* __restrict__ wsu,
                                                 float* __restrict__ qarr,
                                                 float* __restrict__ parr,
                                                 int N) {
    __shared__ int buf[SCAP];
    __shared__ int sbuf[SCAP];
    __shared__ int hist[BW];
    __shared__ int exs[BW];
    __shared__ int curs[BW];
    __shared__ int wtot;
    __shared__ int goff[9];
    const int tid = threadIdx.x;
    const int b = blockIdx.x;
    const int st = b << 12;                 // gapped base

    if (tid == 0) {
        int acc = 0;
        goff[0] = 0;
#pragma unroll
        for (int gg = 0; gg < 8; ++gg) {
            acc += bcnt8[b * 8 + gg];
            goff[gg + 1] = acc;
        }
    }
    if (tid < BW) hist[tid] = 0;
    __syncthreads();
    int cnt = goff[8];
    if (cnt > SCAP) cnt = SCAP;             // never hit (max ~2300); defensive

    for (int i = tid; i < cnt; i += 256) {
        int g = 0;
#pragma unroll
        for (int gg = 1; gg < 8; ++gg) g += (i >= goff[gg]);
        int e = packed[st + (g << 9) + (i - goff[g])];
        buf[i] = e;
        atomicAdd(&hist[e >> 20], 1);
    }
    __syncthreads();

    int v = 0, s = 0;
    if (tid < BW) {
        int lane = tid & 63;
        v = hist[tid];
        s = v;
#pragma unroll
        for (int off = 1; off < 64; off <<= 1) {
            int u = __shfl_up(s, off, 64);
            if (lane >= off) s += u;
        }
        if (tid == 63) wtot = s;
    }
    __syncthreads();
    if (tid < BW) {
        int ex = s - v + ((tid >= 64) ? wtot : 0);
        exs[tid] = ex;
        curs[tid] = ex;
        int node = (b << 7) + tid;
        if (node < N) { nodestart[node] = st + ex; ncnt[node] = v; }
    }
    __syncthreads();

    for (int i = tid; i < cnt; i += 256) {
        int e = buf[i];
        int p = atomicAdd(&curs[e >> 20], 1);
        sbuf[p] = e & 0xFFFFF;
    }
    __syncthreads();
    for (int i = tid; i < cnt; i += 256) csr[st + i] = sbuf[i];  // coalesced

    // ---- Phase B: 4 lanes/node, 2 halves (measured-best form) ----
    const uint2* f2 = (const uint2*)y1b;
    const int seg = tid & 3;
    const float4* wsu4 = (const float4*)wsu;
    const float4 U0 = wsu4[seg];        // u_0[seg*4..]
    const float4 U1 = wsu4[4 + seg];    // u_1
    const float4 U2 = wsu4[8 + seg];    // r_0
    const float4 U3 = wsu4[12 + seg];   // r_1
#pragma unroll
    for (int half = 0; half < 2; ++half) {
        int l = (tid >> 2) + half * 64;
        int node = (b << 7) + l;
        if (node < N) {
            int s0 = exs[l], c = hist[l];
            float ax = 0.f, ay = 0.f, az = 0.f, aw = 0.f;
            int k = 0;
            for (; k + 4 <= c; k += 4) {
                uint2 a = f2[(size_t)(sbuf[s0 + k]     * 4 + seg)];
                uint2 bv = f2[(size_t)(sbuf[s0 + k + 1] * 4 + seg)];
                uint2 cv = f2[(size_t)(sbuf[s0 + k + 2] * 4 + seg)];
                uint2 dv = f2[(size_t)(sbuf[s0 + k + 3] * 4 + seg)];
                ax += (lo16(a.x) + lo16(bv.x)) + (lo16(cv.x) + lo16(dv.x));
                ay += (hi16(a.x) + hi16(bv.x)) + (hi16(cv.x) + hi16(dv.x));
                az += (lo16(a.y) + lo16(bv.y)) + (lo16(cv.y) + lo16(dv.y));
                aw += (hi16(a.y) + hi16(bv.y)) + (hi16(cv.y) + hi16(dv.y));
            }
            for (; k < c; ++k) {
                uint2 a = f2[(size_t)(sbuf[s0 + k] * 4 + seg)];
                ax += lo16(a.x); ay += hi16(a.x);
                az += lo16(a.y); aw += hi16(a.y);
            }
            float inv = 1.f / fmaxf((float)c, 1.f);
            size_t o = (size_t)node * 4 + seg;
            float4 z = ((const float4*)z1)[o];
            float4 bb = ((const float4*)b1)[seg];
            float hx = fmaxf(ax * inv + bb.x + z.x, 0.f);
            float hy = fmaxf(ay * inv + bb.y + z.y, 0.f);
            float hz = fmaxf(az * inv + bb.z + z.z, 0.f);
            float hw = fmaxf(aw * inv + bb.w + z.w, 0.f);
            float d0 = hx * U0.x + hy * U0.y + hz * U0.z + hw * U0.w;
            float d1 = hx * U1.x + hy * U1.y + hz * U1.z + hw * U1.w;
            float d2 = hx * U2.x + hy * U2.y + hz * U2.z + hw * U2.w;
            float d3 = hx * U3.x + hy * U3.y + hz * U3.z + hw * U3.w;
            d0 += __shfl_xor(d0, 1, 4); d0 += __shfl_xor(d0, 2, 4);
            d1 += __shfl_xor(d1, 1, 4); d1 += __shfl_xor(d1, 2, 4);
            d2 += __shfl_xor(d2, 1, 4); d2 += __shfl_xor(d2, 2, 4);
            d3 += __shfl_xor(d3, 1, 4); d3 += __shfl_xor(d3, 2, 4);
            float val = (seg == 0) ? d0 : (seg == 1) ? d1 : (seg == 2) ? d2 : d3;
            float* dp = (seg < 2) ? (qarr + (size_t)seg * N)
                                  : (parr + (size_t)(seg - 2) * N);
            dp[node] = val;
        }
    }
}

// ---------------------------------------------------------------------------
// K6: pair logits + BCE from collapsed scalars. 8 lanes/pair (512 blocks =
// 2 blocks/CU; the 2-lane version ran only 128 blocks = half the GPU idle).
// s = sub>>2 (article slot), part = sub&3 (edge 4-way split).
// ---------------------------------------------------------------------------
__global__ __launch_bounds__(256) void k_pair(const float* __restrict__ qarr,
                                              const float* __restrict__ parr,
                                              const int* __restrict__ csr,
                                              const int* __restrict__ nodestart,
                                              const int* __restrict__ ncnt,
                                              const int* __restrict__ a1,
                                              const int* __restrict__ a2,
                                              const int* __restrict__ labels,
                                              const float* __restrict__ wsu,
                                              float* __restrict__ out_logits,
                                              float* __restrict__ lacc,
                                              int* __restrict__ ticket,
                                              float* __restrict__ out0,
                                              int B, float invB, int N) {
    __shared__ float lred[4];
    int t = blockIdx.x * 256 + threadIdx.x;
    int pid = t >> 3, sub = t & 7;
    int s = sub >> 2, part = sub & 3;

    float hsum = 0.f;
    if (pid < B) {
        int node = s ? a2[pid] : a1[pid];
        int st = nodestart[node];
        int c = ncnt[node];
        const float* qs = qarr + (size_t)s * N;
        const int* ids = csr + st;
        float acc = 0.f;
        int k = part;
        for (; k + 4 < c; k += 8) {              // this lane: edges k, k+4
            int n0 = ids[k], n1 = ids[k + 4];
            acc += qs[n0] + qs[n1];
        }
        if (k < c) acc += qs[ids[k]];
        acc += __shfl_xor(acc, 1, 4);
        acc += __shfl_xor(acc, 2, 4);
        hsum = acc / fmaxf((float)c, 1.f) + parr[(size_t)s * N + node];
    }
    float other = __shfl_xor(hsum, 4, 8);
    float myloss = 0.f;
    if (pid < B && sub == 0) {
        float l = hsum + other + wsu[64] + wsu[65];
        out_logits[pid] = l;
        float y = (float)labels[pid];
        myloss = fmaxf(l, 0.f) - l * y + log1pf(expf(-fabsf(l)));
    }
    // block loss reduction
    float v = myloss;
#pragma unroll
    for (int off = 32; off; off >>= 1) v += __shfl_down(v, off, 64);
    if ((threadIdx.x & 63) == 0) lred[threadIdx.x >> 6] = v;
    __syncthreads();
    if (threadIdx.x == 0) {
        float ssum = lred[0] + lred[1] + lred[2] + lred[3];
        atomicAdd(lacc, ssum);
        __threadfence();
        int tk = atomicAdd(ticket, 1);
        if (tk == (int)gridDim.x - 1) {
            __threadfence();
            float total = atomicAdd(lacc, 0.f);
            out0[0] = total * invB;
        }
    }
}

// ---------------------------------------------------------------------------
extern "C" void kernel_launch(void* const* d_in, const int* in_sizes, int n_in,
                              void* d_out, int out_size, void* d_ws, size_t ws_size,
                              hipStream_t stream) {
    const float* x    = (const float*)d_in[0];
    const float* w1l  = (const float*)d_in[1];
    const float* b1   = (const float*)d_in[2];
    const float* w1r  = (const float*)d_in[3];
    const float* w2l  = (const float*)d_in[4];
    const float* b2v  = (const float*)d_in[5];
    const float* w2r  = (const float*)d_in[6];
    const float* wc   = (const float*)d_in[7];
    const float* bc   = (const float*)d_in[8];
    const int*   ei   = (const int*)d_in[9];
    const int*   a1   = (const int*)d_in[10];
    const int*   a2   = (const int*)d_in[11];
    const int*   lab  = (const int*)d_in[12];

    const int N = in_sizes[0] / DD;
    const int E = in_sizes[9] / 2;
    const int B = in_sizes[10];
    const int NB = (N + BW - 1) / BW;       // 782 for N=100000 (needs N < 2^20)

    const int* src = ei;
    const int* dst = ei + E;

    // workspace layout
    char* ws = (char*)d_ws;
    const size_t PSZ = (size_t)NB * GAPB * 4;                 // gapped packed/csr bytes
    float*    wsu    = (float*)ws;                            // 512 B
    unsigned* y1b    = (unsigned*)(ws + 512);                 // [N,16] bf16 (32 B/row)
    float*    z1     = (float*)   (ws + 512 + (size_t)N * 32);// [N,16] f32
    int*      packed = (int*)     (ws + 512 + (size_t)N * 96);
    int*      csr    = (int*)     (ws + 512 + (size_t)N * 96 + PSZ);
    char*     p4     = ws + 512 + (size_t)N * 96 + 2 * PSZ;
    int*   nodest  = (int*)p4;                               // [N]
    int*   ncnt    = (int*)(p4 + (size_t)N * 4);             // [N]
    float* qarr    = (float*)(p4 + (size_t)N * 8);           // [2N] planes q0,q1
    float* parr    = (float*)(p4 + (size_t)N * 16);          // [2N] planes p0,p1
    int*   bcnt8   = (int*)(p4 + (size_t)N * 24);            // [NB*8] zeroed
    float* lacc    = (float*)(p4 + (size_t)N * 24 + (size_t)NB * 32); // zeroed
    int*   ticket  = (int*)((char*)lacc + 4);                // zeroed

    float* out = (float*)d_out;       // out[0] = loss, out[1..B] = logits

    hipMemsetAsync((void*)bcnt8, 0, (size_t)NB * 32 + 8, stream);

    const int E4 = E / 4;
    const int cblocks = (E4 + 1023) / 1024;          // 4096 edges per chunk

    k_front<<<cblocks + 1 + XG, 256, 0, stream>>>(src, dst, bcnt8, packed,
                                                  E4, NB, cblocks,
                                                  w2l, w2r, b2v, wc, bc, wsu,
                                                  x, w1l, w1r, y1b, z1, N);

    k_sortagg<<<NB, 256, 0, stream>>>(packed, bcnt8, nodest, ncnt, csr,
                                      y1b, z1, b1, wsu, qarr, parr, N);

    k_pair<<<(B * 8 + 255) / 256, 256, 0, stream>>>(qarr, parr, csr, nodest, ncnt,
                                                    a1, a2, lab, wsu,
                                                    out + 1, lacc, ticket, out,
                                                    B, 1.0f / (float)B, N);
}

// Round 11
// 164.073 us; speedup vs baseline: 1.1967x; 1.1514x over previous
//
#include <hip/hip_runtime.h>
#include <hip/hip_bf16.h>

#define DD 128    // feature dim
#define HH 16     // hidden dim
#define BW 128    // bucket width (nodes per bucket) = 1<<7
#define NBMAX 1024
#define SCAP 4096      // LDS slice cap in sortagg
#define XG 384         // xform blocks in k_front

// bf16x2 pack/unpack (RNE)
__device__ __forceinline__ float lo16(unsigned u) { return __uint_as_float(u << 16); }
__device__ __forceinline__ float hi16(unsigned u) { return __uint_as_float(u & 0xffff0000u); }
__device__ __forceinline__ unsigned b16(float f) {
    unsigned u = __float_as_uint(f);
    return (u + 0x7fffu + ((u >> 16) & 1u)) >> 16;
}
__device__ __forceinline__ unsigned pack2(float a, float b) {
    return b16(a) | (b16(b) << 16);
}

typedef __attribute__((ext_vector_type(8))) short bf16x8;   // MFMA A/B frag (4 VGPRs)
typedef __attribute__((ext_vector_type(4))) float f32x4;    // MFMA C/D frag

// ---------------------------------------------------------------------------
// K1 (k_front): fused front (R5 174.8us structure). Three block roles:
//   [0, cblocks)  : LOCAL-SORT scatter. Each block counting-sorts its 4096
//                   edges by bucket IN LDS (hist -> 1024-wide exclusive scan
//                   -> sbuf), then writes them CONTIGUOUSLY to
//                   packed[bid*4096..] (coalesced stream) and publishes the
//                   per-bucket offsets runofs[bid*1024 + b] (b in [0,NB]).
//                   No scattered global writes, no global atomics — the
//                   44us-invariant dependent chain (LDS-atomic -> scattered
//                   4B store) is gone.
//   cblocks       : classifier-collapse prep (wsu[0..65]).
//   (cblocks,+XG] : xform y1 = x@w1_l (bf16), z1 = x@w1_r (f32) via MFMA,
//                   single-buffered (load->pack->MFMA fused).
// ---------------------------------------------------------------------------
__global__ __launch_bounds__(256)
__attribute__((amdgpu_waves_per_eu(1, 4)))
void k_front(const int* __restrict__ src,
             const int* __restrict__ dst,
             int* __restrict__ packed,
             int* __restrict__ runofs,
             int E4, int NB, int cblocks,
             const float* __restrict__ w2l,
             const float* __restrict__ w2r,
             const float* __restrict__ b2v,
             const float* __restrict__ wc,
             const float* __restrict__ bc,
             float* __restrict__ wsu,
             const float* __restrict__ x,
             const float* __restrict__ w1l,
             const float* __restrict__ w1r,
             unsigned* __restrict__ y1b,
             float* __restrict__ z1, int N) {
    __shared__ int hist[NBMAX];
    __shared__ int lofs[NBMAX];    // exclusive offsets; mutated as cursors
    __shared__ int sbuf[4096];
    __shared__ int wss[4];
    const int tid = threadIdx.x;
    const int bid = (int)blockIdx.x;

    if (bid == cblocks) {      // ---- prep block ----
        if (tid < 64) {
            int k = tid >> 4, j = tid & 15;
            const float* W = (k < 2) ? w2l : w2r;
            int off = (k & 1) * DD;
            float s = 0.f;
            for (int d = 0; d < DD; ++d) s += W[j * DD + d] * wc[off + d];
            wsu[k * 16 + j] = s;
        } else if (tid == 64) {
            float s = bc[0];
            for (int d = 0; d < DD; ++d) s += b2v[d] * wc[d];
            wsu[64] = s;
        } else if (tid == 65) {
            float s = 0.f;
            for (int d = 0; d < DD; ++d) s += b2v[d] * wc[DD + d];
            wsu[65] = s;
        }
        return;
    }

    if (bid > cblocks) {       // ---- xform blocks (single-buffered, reg-light) ----
        const int xb   = bid - cblocks - 1;          // 0..XG-1
        const int lane = tid & 63;
        const int m    = lane & 15;
        const int quad = lane >> 4;
        const int nw   = XG * 4;                     // total xform waves
        const int wid  = xb * 4 + (tid >> 6);
        const int ntiles = N >> 4;

        bf16x8 AL[4], AR[4];
#pragma unroll
        for (int kk = 0; kk < 4; ++kk) {
            union { unsigned u[4]; bf16x8 v; } al, ar;
#pragma unroll
            for (int p = 0; p < 4; ++p) {
                int d0 = kk * 32 + quad * 8 + 2 * p;
                al.u[p] = pack2(w1l[(size_t)d0 * HH + m], w1l[(size_t)(d0 + 1) * HH + m]);
                ar.u[p] = pack2(w1r[(size_t)d0 * HH + m], w1r[(size_t)(d0 + 1) * HH + m]);
            }
            AL[kk] = al.v; AR[kk] = ar.v;
        }

        const float4* xg4 = (const float4*)x;
        for (int tile = wid; tile < ntiles; tile += nw) {
            f32x4 accL = {0.f, 0.f, 0.f, 0.f};
            f32x4 accR = {0.f, 0.f, 0.f, 0.f};
#pragma unroll
            for (int kk = 0; kk < 4; ++kk) {
                size_t o = (size_t)(tile * 16 + m) * 32 + kk * 8 + quad * 2;
                float4 a = xg4[o], b = xg4[o + 1];
                union { unsigned u[4]; bf16x8 v; } bx;
                bx.u[0] = pack2(a.x, a.y);
                bx.u[1] = pack2(a.z, a.w);
                bx.u[2] = pack2(b.x, b.y);
                bx.u[3] = pack2(b.z, b.w);
                accL = __builtin_amdgcn_mfma_f32_16x16x32_bf16(AL[kk], bx.v, accL, 0, 0, 0);
                accR = __builtin_amdgcn_mfma_f32_16x16x32_bf16(AR[kk], bx.v, accR, 0, 0, 0);
            }
            int row = tile * 16 + m;
            uint2 yp; yp.x = pack2(accL[0], accL[1]); yp.y = pack2(accL[2], accL[3]);
            ((uint2*)y1b)[(size_t)row * 4 + quad] = yp;
            float4 zf = {accR[0], accR[1], accR[2], accR[3]};
            ((float4*)z1)[(size_t)row * 4 + quad] = zf;
        }

        // scalar tail for N % 16 (not hit when N % 16 == 0)
        const int tail0 = ntiles << 4;
        if (tail0 < N && xb == 0) {
            for (int idx = tid; idx < (N - tail0) * HH; idx += 256) {
                int row = tail0 + (idx >> 4), n = idx & 15;
                float sl = 0.f, sr = 0.f;
                for (int d = 0; d < DD; ++d) {
                    float xv = x[(size_t)row * DD + d];
                    sl += xv * w1l[(size_t)d * HH + n];
                    sr += xv * w1r[(size_t)d * HH + n];
                }
                ((unsigned short*)y1b)[(size_t)row * 16 + n] = (unsigned short)b16(sl);
                z1[(size_t)row * HH + n] = sr;
            }
        }
        return;
    }

    // ---- scat blocks: local counting sort + coalesced write ----
    for (int i = tid; i < NBMAX; i += 256) hist[i] = 0;   // zero-pad for scan
    __syncthreads();
    int base = bid * 1024;                                // int4 units
    int4 dreg[4];
#pragma unroll
    for (int k = 0; k < 4; ++k) {
        int i4 = base + k * 256 + tid;
        if (i4 < E4) {
            int4 d = ((const int4*)dst)[i4];
            dreg[k] = d;
            atomicAdd(&hist[d.x >> 7], 1);
            atomicAdd(&hist[d.y >> 7], 1);
            atomicAdd(&hist[d.z >> 7], 1);
            atomicAdd(&hist[d.w >> 7], 1);
        }
    }
    __syncthreads();
    // exclusive scan of 1024 entries (4/thread + wave scan + combine)
    {
        int cb = tid * 4;
        int a0 = hist[cb], a1 = hist[cb + 1], a2 = hist[cb + 2], a3 = hist[cb + 3];
        int s1 = a0 + a1, s2 = s1 + a2, tot = s2 + a3;
        int lane = tid & 63;
        int inc = tot;
#pragma unroll
        for (int off = 1; off < 64; off <<= 1) {
            int u = __shfl_up(inc, off, 64);
            if (lane >= off) inc += u;
        }
        if (lane == 63) wss[tid >> 6] = inc;
        __syncthreads();
        int w = tid >> 6, woff = 0;
#pragma unroll
        for (int k2 = 0; k2 < 4; ++k2) if (k2 < w) woff += wss[k2];
        int e0 = woff + inc - tot;
        lofs[cb]     = e0;
        lofs[cb + 1] = e0 + a0;
        lofs[cb + 2] = e0 + s1;
        lofs[cb + 3] = e0 + s2;
    }
    __syncthreads();
    // publish per-(block,bucket) offsets BEFORE cursors mutate (coalesced)
    for (int b2 = tid; b2 <= NB; b2 += 256)
        runofs[(size_t)bid * 1024 + b2] = lofs[b2];
    __syncthreads();
    // counting-sort into sbuf (lofs doubles as cursor array)
#pragma unroll
    for (int k = 0; k < 4; ++k) {
        int i4 = base + k * 256 + tid;
        if (i4 < E4) {
            int4 sv = ((const int4*)src)[i4];
            int4 d = dreg[k];
            int p;
            p = atomicAdd(&lofs[d.x >> 7], 1); sbuf[p] = ((d.x & 127) << 20) | sv.x;
            p = atomicAdd(&lofs[d.y >> 7], 1); sbuf[p] = ((d.y & 127) << 20) | sv.y;
            p = atomicAdd(&lofs[d.z >> 7], 1); sbuf[p] = ((d.z & 127) << 20) | sv.z;
            p = atomicAdd(&lofs[d.w >> 7], 1); sbuf[p] = ((d.w & 127) << 20) | sv.w;
        }
    }
    __syncthreads();
    // coalesced stream write of the sorted block
    int rem = (E4 - base) * 4;
    int ec = rem < 4096 ? rem : 4096;
    for (int i = tid; i < ec; i += 256)
        packed[(size_t)bid * 4096 + i] = sbuf[i];
}

// ---------------------------------------------------------------------------
// K5: one block per bucket. The bucket's edges live in cblocks runs:
// run g at packed[g*4096 + runofs[g*1024+b] .. +runofs[g*1024+b+1]).
// Phase A: 2 runs/thread, wave scan of run counts for in-bucket placement,
// gather runs into LDS buf (+node hist), then counting sort -> sbuf,
// nodestart/ncnt/csr (csr stays gapped at b<<12).
// Phase B (R5 measured-best 4-lane uint2 form): layer-1 mean ->
// h = relu(mean + b1 + z1) -> classifier collapse q_s = h.u_s, p_s = h.r_s.
// ---------------------------------------------------------------------------
__global__ __launch_bounds__(256) void k_sortagg(const int* __restrict__ packed,
                                                 const int* __restrict__ runofs,
                                                 int cblocks,
                                                 int* __restrict__ nodestart,
                                                 int* __restrict__ ncnt,
                                                 int* __restrict__ csr,
                                                 const unsigned* __restrict__ y1b,
                                                 const float* __restrict__ z1,
                                                 const float* __restrict__ b1,
                                                 const float* __restrict__ wsu,
                                                 float* __restrict__ qarr,
                                                 float* __restrict__ parr,
                                                 int N) {
    __shared__ int buf[SCAP];
    __shared__ int sbuf[SCAP];
    __shared__ int hist[BW];
    __shared__ int exs[BW];
    __shared__ int curs[BW];
    __shared__ int wss[4];
    __shared__ int wtot;
    const int tid = threadIdx.x;
    const int b = blockIdx.x;
    const int st = b << 12;                 // gapped csr base

    if (tid < BW) hist[tid] = 0;

    // ---- run descriptors: 2 runs per thread ----
    const int r0 = tid * 2, r1 = r0 + 1;
    int s0g = 0, c0 = 0, s1g = 0, c1 = 0;
    if (r0 < cblocks) {
        s0g = runofs[(size_t)r0 * 1024 + b];
        c0  = runofs[(size_t)r0 * 1024 + b + 1] - s0g;
    }
    if (r1 < cblocks) {
        s1g = runofs[(size_t)r1 * 1024 + b];
        c1  = runofs[(size_t)r1 * 1024 + b + 1] - s1g;
    }
    int pr = c0 + c1;
    int lane = tid & 63;
    int inc = pr;
#pragma unroll
    for (int off = 1; off < 64; off <<= 1) {
        int u = __shfl_up(inc, off, 64);
        if (lane >= off) inc += u;
    }
    if (lane == 63) wss[tid >> 6] = inc;
    __syncthreads();                         // also covers hist zeroing
    int w = tid >> 6, woff = 0;
#pragma unroll
    for (int k2 = 0; k2 < 4; ++k2) if (k2 < w) woff += wss[k2];
    int excl = woff + inc - pr;              // buf position for run r0
    int cnt = wss[0] + wss[1] + wss[2] + wss[3];
    if (cnt > SCAP) cnt = SCAP;              // never hit (max ~2300); defensive

    // ---- gather this thread's two runs into buf (+ node hist) ----
    for (int j = 0; j < c0; ++j) {
        int e = packed[(size_t)r0 * 4096 + s0g + j];
        buf[excl + j] = e;
        atomicAdd(&hist[e >> 20], 1);
    }
    int exb = excl + c0;
    for (int j = 0; j < c1; ++j) {
        int e = packed[(size_t)r1 * 4096 + s1g + j];
        buf[exb + j] = e;
        atomicAdd(&hist[e >> 20], 1);
    }
    __syncthreads();

    // ---- node-level exclusive scan (128 entries) ----
    int v = 0, s = 0;
    if (tid < BW) {
        v = hist[tid];
        s = v;
#pragma unroll
        for (int off = 1; off < 64; off <<= 1) {
            int u = __shfl_up(s, off, 64);
            if (lane >= off) s += u;
        }
        if (tid == 63) wtot = s;
    }
    __syncthreads();
    if (tid < BW) {
        int ex = s - v + ((tid >= 64) ? wtot : 0);
        exs[tid] = ex;
        curs[tid] = ex;
        int node = (b << 7) + tid;
        if (node < N) { nodestart[node] = st + ex; ncnt[node] = v; }
    }
    __syncthreads();

    for (int i = tid; i < cnt; i += 256) {
        int e = buf[i];
        int p = atomicAdd(&curs[e >> 20], 1);
        sbuf[p] = e & 0xFFFFF;
    }
    __syncthreads();
    for (int i = tid; i < cnt; i += 256) csr[st + i] = sbuf[i];  // coalesced

    // ---- Phase B: 4 lanes/node, 2 halves (R5 measured-best form) ----
    const uint2* f2 = (const uint2*)y1b;
    const int seg = tid & 3;
    const float4* wsu4 = (const float4*)wsu;
    const float4 U0 = wsu4[seg];        // u_0[seg*4..]
    const float4 U1 = wsu4[4 + seg];    // u_1
    const float4 U2 = wsu4[8 + seg];    // r_0
    const float4 U3 = wsu4[12 + seg];   // r_1
#pragma unroll
    for (int half = 0; half < 2; ++half) {
        int l = (tid >> 2) + half * 64;
        int node = (b << 7) + l;
        if (node < N) {
            int s0 = exs[l], c = hist[l];
            float ax = 0.f, ay = 0.f, az = 0.f, aw = 0.f;
            int k = 0;
            for (; k + 4 <= c; k += 4) {
                uint2 a = f2[(size_t)(sbuf[s0 + k]     * 4 + seg)];
                uint2 bv = f2[(size_t)(sbuf[s0 + k + 1] * 4 + seg)];
                uint2 cv = f2[(size_t)(sbuf[s0 + k + 2] * 4 + seg)];
                uint2 dv = f2[(size_t)(sbuf[s0 + k + 3] * 4 + seg)];
                ax += (lo16(a.x) + lo16(bv.x)) + (lo16(cv.x) + lo16(dv.x));
                ay += (hi16(a.x) + hi16(bv.x)) + (hi16(cv.x) + hi16(dv.x));
                az += (lo16(a.y) + lo16(bv.y)) + (lo16(cv.y) + lo16(dv.y));
                aw += (hi16(a.y) + hi16(bv.y)) + (hi16(cv.y) + hi16(dv.y));
            }
            for (; k < c; ++k) {
                uint2 a = f2[(size_t)(sbuf[s0 + k] * 4 + seg)];
                ax += lo16(a.x); ay += hi16(a.x);
                az += lo16(a.y); aw += hi16(a.y);
            }
            float inv = 1.f / fmaxf((float)c, 1.f);
            size_t o = (size_t)node * 4 + seg;
            float4 z = ((const float4*)z1)[o];
            float4 bb = ((const float4*)b1)[seg];
            float hx = fmaxf(ax * inv + bb.x + z.x, 0.f);
            float hy = fmaxf(ay * inv + bb.y + z.y, 0.f);
            float hz = fmaxf(az * inv + bb.z + z.z, 0.f);
            float hw = fmaxf(aw * inv + bb.w + z.w, 0.f);
            float d0 = hx * U0.x + hy * U0.y + hz * U0.z + hw * U0.w;
            float d1 = hx * U1.x + hy * U1.y + hz * U1.z + hw * U1.w;
            float d2 = hx * U2.x + hy * U2.y + hz * U2.z + hw * U2.w;
            float d3 = hx * U3.x + hy * U3.y + hz * U3.z + hw * U3.w;
            d0 += __shfl_xor(d0, 1, 4); d0 += __shfl_xor(d0, 2, 4);
            d1 += __shfl_xor(d1, 1, 4); d1 += __shfl_xor(d1, 2, 4);
            d2 += __shfl_xor(d2, 1, 4); d2 += __shfl_xor(d2, 2, 4);
            d3 += __shfl_xor(d3, 1, 4); d3 += __shfl_xor(d3, 2, 4);
            float val = (seg == 0) ? d0 : (seg == 1) ? d1 : (seg == 2) ? d2 : d3;
            float* dp = (seg < 2) ? (qarr + (size_t)seg * N)
                                  : (parr + (size_t)(seg - 2) * N);
            dp[node] = val;
        }
    }
}

// ---------------------------------------------------------------------------
// K6: pair logits + BCE from collapsed scalars (R5 measured-best form).
// 2 lanes per pair (s = article slot). Per edge: ONE 4 B gather from the
// 400 KB q-plane (L2-resident).
// ---------------------------------------------------------------------------
__global__ __launch_bounds__(256) void k_pair(const float* __restrict__ qarr,
                                              const float* __restrict__ parr,
                                              const int* __restrict__ csr,
                                              const int* __restrict__ nodestart,
                                              const int* __restrict__ ncnt,
                                              const int* __restrict__ a1,
                                              const int* __restrict__ a2,
                                              const int* __restrict__ labels,
                                              const float* __restrict__ wsu,
                                              float* __restrict__ out_logits,
                                              float* __restrict__ lacc,
                                              int* __restrict__ ticket,
                                              float* __restrict__ out0,
                                              int B, float invB, int N) {
    __shared__ float lred[4];
    int t = blockIdx.x * 256 + threadIdx.x;
    int pid = t >> 1, s = t & 1;

    float hsum = 0.f;
    if (pid < B) {
        int node = s ? a2[pid] : a1[pid];
        int st = nodestart[node];
        int c = ncnt[node];
        const float* qs = qarr + (size_t)s * N;
        const int* ids = csr + st;
        float acc = 0.f;
        int k = 0;
        for (; k + 4 <= c; k += 4) {
            int n0 = ids[k], n1 = ids[k + 1], n2 = ids[k + 2], n3 = ids[k + 3];
            acc += (qs[n0] + qs[n1]) + (qs[n2] + qs[n3]);
        }
        for (; k < c; ++k) acc += qs[ids[k]];
        hsum = acc / fmaxf((float)c, 1.f) + parr[(size_t)s * N + node];
    }
    float other = __shfl_xor(hsum, 1, 2);
    float myloss = 0.f;
    if (pid < B && s == 0) {
        float l = hsum + other + wsu[64] + wsu[65];
        out_logits[pid] = l;
        float y = (float)labels[pid];
        myloss = fmaxf(l, 0.f) - l * y + log1pf(expf(-fabsf(l)));
    }
    // block loss reduction
    float v = myloss;
#pragma unroll
    for (int off = 32; off; off >>= 1) v += __shfl_down(v, off, 64);
    if ((threadIdx.x & 63) == 0) lred[threadIdx.x >> 6] = v;
    __syncthreads();
    if (threadIdx.x == 0) {
        float ssum = lred[0] + lred[1] + lred[2] + lred[3];
        atomicAdd(lacc, ssum);
        __threadfence();
        int tk = atomicAdd(ticket, 1);
        if (tk == (int)gridDim.x - 1) {
            __threadfence();
            float total = atomicAdd(lacc, 0.f);
            out0[0] = total * invB;
        }
    }
}

// ---------------------------------------------------------------------------
extern "C" void kernel_launch(void* const* d_in, const int* in_sizes, int n_in,
                              void* d_out, int out_size, void* d_ws, size_t ws_size,
                              hipStream_t stream) {
    const float* x    = (const float*)d_in[0];
    const float* w1l  = (const float*)d_in[1];
    const float* b1   = (const float*)d_in[2];
    const float* w1r  = (const float*)d_in[3];
    const float* w2l  = (const float*)d_in[4];
    const float* b2v  = (const float*)d_in[5];
    const float* w2r  = (const float*)d_in[6];
    const float* wc   = (const float*)d_in[7];
    const float* bc   = (const float*)d_in[8];
    const int*   ei   = (const int*)d_in[9];
    const int*   a1   = (const int*)d_in[10];
    const int*   a2   = (const int*)d_in[11];
    const int*   lab  = (const int*)d_in[12];

    const int N = in_sizes[0] / DD;
    const int E = in_sizes[9] / 2;
    const int B = in_sizes[10];
    const int NB = (N + BW - 1) / BW;       // 782 for N=100000 (needs N < 2^20)

    const int* src = ei;
    const int* dst = ei + E;

    const int E4 = E / 4;
    const int cblocks = (E4 + 1023) / 1024;          // 4096 edges per chunk

    // workspace layout
    char* ws = (char*)d_ws;
    float*    wsu    = (float*)ws;                            // 512 B
    unsigned* y1b    = (unsigned*)(ws + 512);                 // [N,16] bf16 (32 B/row)
    float*    z1     = (float*)   (ws + 512 + (size_t)N * 32);// [N,16] f32
    int*      packed = (int*)     (ws + 512 + (size_t)N * 96);// [cblocks*4096] sorted blocks
    const size_t PKSZ = (size_t)cblocks * 4096 * 4;
    int*      runofs = (int*)((char*)packed + PKSZ);          // [cblocks*1024] offsets
    const size_t RSZ  = (size_t)cblocks * 1024 * 4;
    int*      csr    = (int*)((char*)runofs + RSZ);           // [NB*4096] gapped
    const size_t CSZ  = (size_t)NB * 4096 * 4;
    char*     p4     = (char*)csr + CSZ;
    int*   nodest  = (int*)p4;                               // [N]
    int*   ncnt    = (int*)(p4 + (size_t)N * 4);             // [N]
    float* qarr    = (float*)(p4 + (size_t)N * 8);           // [2N] planes q0,q1
    float* parr    = (float*)(p4 + (size_t)N * 16);          // [2N] planes p0,p1
    float* lacc    = (float*)(p4 + (size_t)N * 24);          // zeroed
    int*   ticket  = (int*)((char*)lacc + 4);                // zeroed

    float* out = (float*)d_out;       // out[0] = loss, out[1..B] = logits

    hipMemsetAsync((void*)lacc, 0, 8, stream);

    k_front<<<cblocks + 1 + XG, 256, 0, stream>>>(src, dst, packed, runofs,
                                                  E4, NB, cblocks,
                                                  w2l, w2r, b2v, wc, bc, wsu,
                                                  x, w1l, w1r, y1b, z1, N);

    k_sortagg<<<NB, 256, 0, stream>>>(packed, runofs, cblocks,
                                      nodest, ncnt, csr,
                                      y1b, z1, b1, wsu, qarr, parr, N);

    k_pair<<<(B * 2 + 255) / 256, 256, 0, stream>>>(qarr, parr, csr, nodest, ncnt,
                                                    a1, a2, lab, wsu,
                                                    out + 1, lacc, ticket, out,
                                                    B, 1.0f / (float)B, N);
}